// Round 10
// baseline (147.848 us; speedup 1.0000x reference)
//
#include <hip/hip_runtime.h>

#define B_ 2048
#define T_ 256
#define F_ 64
#define EMB_ 16
#define UNITS_ 32
#define L2E 1.44269504f

typedef __attribute__((ext_vector_type(8))) short bf16x8;
typedef __attribute__((ext_vector_type(4))) float f32x4;

__device__ __forceinline__ unsigned short f2bf(float f) {  // RNE float->bf16
    unsigned u = __float_as_uint(f);
    return (unsigned short)((u + 0x7FFFu + ((u >> 16) & 1u)) >> 16);
}
__device__ __forceinline__ float fast_sigmoid(float x) {
    return __builtin_amdgcn_rcpf(1.0f + __builtin_amdgcn_exp2f(-L2E * x));
}

// Fused LSTM: embedding produced in-register 4 steps ahead of the recurrence,
// inside its latency shadow. One WG (4 waves) per 16-row batch tile; 128 WGs.
// Rec structure = round-5 (verified, best measured): wave w owns units
// [8w,8w+8) as 2 M-tiles (tau); lane (g,m15) owns cells (units 8w+2g+tau,
// batch m15), gates in acc rows 4g+r; parity-buffered hx; ONE lgkm-only
// barrier per step (+sched_barrier(0) fence, rule #18); single h-dependent
// MFMA (Fe precomputed one step ahead). A/bias pre-scaled by -L2E (c rows
// -2L2E) so MFMA output feeds exp2 directly.
// Embed: C-output of mfma(Wemb-frag, x-frag) at lane (g,m15) is exactly this
// lane's Be fragment (rows 4g+r = emb dims, col m15 = batch). produce() uses
// the r3-r8-verified f2bf path only (no inline asm).
__global__ __launch_bounds__(256) void lstm_fused(
    const float* __restrict__ x,
    const float* __restrict__ Wemb, const float* __restrict__ bemb,
    const float* __restrict__ Wf, const float* __restrict__ bfv,
    const float* __restrict__ Wi, const float* __restrict__ biv,
    const float* __restrict__ Wc, const float* __restrict__ bcv,
    const float* __restrict__ Wo, const float* __restrict__ bov,
    const float* __restrict__ Wout, const float* __restrict__ bout,
    float* __restrict__ out)
{
    __shared__ unsigned short hx[2][16][36];   // [parity][batch][unit], padded
    __shared__ float pred[4][16];

    const int tid = threadIdx.x;
    const int w = tid >> 6;
    const int lane = tid & 63;
    const int g = lane >> 4, m15 = lane & 15;
    const int bt = blockIdx.x;

    // ---- rec weight fragments (r5 mapping, pre-scaled) ----
    const int gate = m15 & 3;
    const float* Wsel = (gate == 0) ? Wf : (gate == 1) ? Wi : (gate == 2) ? Wc : Wo;
    const float ascale = (gate == 2) ? (-2.0f * L2E) : (-L2E);
    const int uAb = 8 * w + 2 * (m15 >> 2);

    bf16x8 Ah[2], Ae[2];
    #pragma unroll
    for (int tau = 0; tau < 2; ++tau) {
        const int uA = uAb + tau;
        #pragma unroll
        for (int j = 0; j < 4; ++j) {
            Ah[tau][j]     = (short)f2bf(ascale * Wsel[(4 * g + j) * UNITS_ + uA]);
            Ah[tau][j + 4] = (short)f2bf(ascale * Wsel[(16 + 4 * g + j) * UNITS_ + uA]);
            Ae[tau][j]     = (short)f2bf(ascale * Wsel[(32 + 4 * g + j) * UNITS_ + uA]);
            Ae[tau][j + 4] = 0;
        }
    }
    f32x4 bias[2];
    #pragma unroll
    for (int tau = 0; tau < 2; ++tau) {
        const int u = 8 * w + 2 * g + tau;
        bias[tau][0] = -L2E * bfv[u];
        bias[tau][1] = -L2E * biv[u];
        bias[tau][2] = -2.0f * L2E * bcv[u];
        bias[tau][3] = -L2E * bov[u];
    }

    // ---- embed weight fragments (unscaled) ----
    bf16x8 Ea1, Ea2;
    #pragma unroll
    for (int j = 0; j < 4; ++j) {
        Ea1[j]     = (short)f2bf(Wemb[(4 * g + j) * EMB_ + m15]);
        Ea1[j + 4] = (short)f2bf(Wemb[(16 + 4 * g + j) * EMB_ + m15]);
        Ea2[j]     = (short)f2bf(Wemb[(32 + 4 * g + j) * EMB_ + m15]);
        Ea2[j + 4] = (short)f2bf(Wemb[(48 + 4 * g + j) * EMB_ + m15]);
    }
    f32x4 bce;
    #pragma unroll
    for (int r = 0; r < 4; ++r) bce[r] = bemb[4 * g + r];

    // ---- helpers ----
    auto mkBe = [](uint2 ev) -> bf16x8 {
        return bf16x8{(short)(ev.x & 0xffff), (short)(ev.x >> 16),
                      (short)(ev.y & 0xffff), (short)(ev.y >> 16), 0, 0, 0, 0};
    };
    auto cell = [&](const f32x4& acc, float& cst, float& hf) {
        float Ef = __builtin_amdgcn_exp2f(acc[0]);
        float Ei = __builtin_amdgcn_exp2f(acc[1]);
        float Ec = __builtin_amdgcn_exp2f(acc[2]);
        float Eo = __builtin_amdgcn_exp2f(acc[3]);
        float Pf = 1.f + Ef, Pi = 1.f + Ei, Pc = 1.f + Ec, Po = 1.f + Eo;
        float Mc = 1.f - Ec;
        float t1 = Pi * Pc;
        float num = fmaf(cst, t1, Pf * Mc);
        float den = Pf * t1;
        float cn = num * __builtin_amdgcn_rcpf(den);
        cst = cn;
        float Eh = __builtin_amdgcn_exp2f(cn * (-2.0f * L2E));
        float Mh = 1.f - Eh;
        float d2 = (1.f + Eh) * Po;
        hf = Mh * __builtin_amdgcn_rcpf(d2);
    };

    const float* xb = x + (size_t)(bt * 16 + m15) * T_ * F_;
    // embed one timestep from 4 register float4s (r3-r8-verified f2bf path)
    auto produce = [&](float4 q0, float4 q1, float4 q2, float4 q3) -> uint2 {
        bf16x8 B1 = {(short)f2bf(q0.x), (short)f2bf(q0.y),
                     (short)f2bf(q0.z), (short)f2bf(q0.w),
                     (short)f2bf(q1.x), (short)f2bf(q1.y),
                     (short)f2bf(q1.z), (short)f2bf(q1.w)};
        bf16x8 B2 = {(short)f2bf(q2.x), (short)f2bf(q2.y),
                     (short)f2bf(q2.z), (short)f2bf(q2.w),
                     (short)f2bf(q3.x), (short)f2bf(q3.y),
                     (short)f2bf(q3.z), (short)f2bf(q3.w)};
        f32x4 a = __builtin_amdgcn_mfma_f32_16x16x32_bf16(Ea1, B1, bce, 0, 0, 0);
        a = __builtin_amdgcn_mfma_f32_16x16x32_bf16(Ea2, B2, a, 0, 0, 0);
        unsigned u0 = (unsigned)f2bf(fast_sigmoid(a[0])) |
                      ((unsigned)f2bf(fast_sigmoid(a[1])) << 16);
        unsigned u1 = (unsigned)f2bf(fast_sigmoid(a[2])) |
                      ((unsigned)f2bf(fast_sigmoid(a[3])) << 16);
        return make_uint2(u0, u1);
    };

    // ---- prologue: e(0..3) in ring; x(4),x(5) in registers ----
    uint2 ering[4];
    #pragma unroll
    for (int p = 0; p < 4; ++p) {
        const float* xp = xb + (size_t)p * F_;
        float4 q0 = *(const float4*)(xp + 4 * g);
        float4 q1 = *(const float4*)(xp + 16 + 4 * g);
        float4 q2 = *(const float4*)(xp + 32 + 4 * g);
        float4 q3 = *(const float4*)(xp + 48 + 4 * g);
        ering[p] = produce(q0, q1, q2, q3);
    }
    float4 xA0, xA1, xA2, xA3, xB0, xB1, xB2, xB3;
    {
        const float* p4 = xb + (size_t)4 * F_;
        xA0 = *(const float4*)(p4 + 4 * g);      xA1 = *(const float4*)(p4 + 16 + 4 * g);
        xA2 = *(const float4*)(p4 + 32 + 4 * g); xA3 = *(const float4*)(p4 + 48 + 4 * g);
        const float* p5 = xb + (size_t)5 * F_;
        xB0 = *(const float4*)(p5 + 4 * g);      xB1 = *(const float4*)(p5 + 16 + 4 * g);
        xB2 = *(const float4*)(p5 + 32 + 4 * g); xB3 = *(const float4*)(p5 + 48 + 4 * g);
    }

    for (int i = tid; i < 2 * 16 * 36 / 2; i += 256) ((unsigned*)hx)[i] = 0;
    __syncthreads();

    float c0 = 0.f, c1 = 0.f, hf0 = 0.f, hf1 = 0.f;

    f32x4 Fe0, Fe1;
    {
        bf16x8 Be = mkBe(ering[0]);
        Fe0 = __builtin_amdgcn_mfma_f32_16x16x32_bf16(Ae[0], Be, bias[0], 0, 0, 0);
        Fe1 = __builtin_amdgcn_mfma_f32_16x16x32_bf16(Ae[1], Be, bias[1], 0, 0, 0);
    }

#define STEP(S, XQ0, XQ1, XQ2, XQ3)                                            \
    do {                                                                       \
        const int u = t + (S);                                                 \
        const unsigned short* hrow = &hx[u & 1][m15][0];                       \
        ushort4 hlo = *(const ushort4*)(hrow + 4 * g);                         \
        ushort4 hhi = *(const ushort4*)(hrow + 16 + 4 * g);                    \
        bf16x8 Bh = {(short)hlo.x, (short)hlo.y, (short)hlo.z, (short)hlo.w,   \
                     (short)hhi.x, (short)hhi.y, (short)hhi.z, (short)hhi.w};  \
        f32x4 a0 = __builtin_amdgcn_mfma_f32_16x16x32_bf16(Ah[0], Bh, Fe0, 0, 0, 0); \
        f32x4 a1 = __builtin_amdgcn_mfma_f32_16x16x32_bf16(Ah[1], Bh, Fe1, 0, 0, 0); \
        {                                                                      \
            bf16x8 Be = mkBe(ering[((S) + 1) & 3]);                            \
            Fe0 = __builtin_amdgcn_mfma_f32_16x16x32_bf16(Ae[0], Be, bias[0], 0, 0, 0); \
            Fe1 = __builtin_amdgcn_mfma_f32_16x16x32_bf16(Ae[1], Be, bias[1], 0, 0, 0); \
        }                                                                      \
        ering[(S) & 3] = produce(XQ0, XQ1, XQ2, XQ3);                          \
        {                                                                      \
            int lx = (u + 6 < T_) ? u + 6 : T_ - 1;                            \
            const float* p = xb + (size_t)lx * F_;                             \
            XQ0 = *(const float4*)(p + 4 * g);                                 \
            XQ1 = *(const float4*)(p + 16 + 4 * g);                            \
            XQ2 = *(const float4*)(p + 32 + 4 * g);                            \
            XQ3 = *(const float4*)(p + 48 + 4 * g);                            \
        }                                                                      \
        cell(a0, c0, hf0);                                                     \
        cell(a1, c1, hf1);                                                     \
        unsigned pk;                                                           \
        asm("v_cvt_pk_bf16_f32 %0, %1, %2" : "=v"(pk) : "v"(hf0), "v"(hf1));   \
        *(unsigned*)&hx[(u + 1) & 1][m15][8 * w + 2 * g] = pk;                 \
        asm volatile("s_waitcnt lgkmcnt(0)\n\ts_barrier" ::: "memory");        \
        __builtin_amdgcn_sched_barrier(0);                                     \
    } while (0)

    #pragma unroll 1
    for (int t = 0; t < T_; t += 4) {
        STEP(0, xA0, xA1, xA2, xA3);
        STEP(1, xB0, xB1, xB2, xB3);
        STEP(2, xA0, xA1, xA2, xA3);
        STEP(3, xB0, xB1, xB2, xB3);
    }
#undef STEP

    // ---- output projection ----
    float p = hf0 * Wout[8 * w + 2 * g] + hf1 * Wout[8 * w + 2 * g + 1];
    p += __shfl_xor(p, 16, 64);
    p += __shfl_xor(p, 32, 64);
    if (lane < 16) pred[w][lane] = p;
    __syncthreads();
    if (tid < 16)
        out[bt * 16 + tid] = fast_sigmoid(pred[0][tid] + pred[1][tid] +
                                          pred[2][tid] + pred[3][tid] + bout[0]);
}

extern "C" void kernel_launch(void* const* d_in, const int* in_sizes, int n_in,
                              void* d_out, int out_size, void* d_ws, size_t ws_size,
                              hipStream_t stream) {
    const float* x    = (const float*)d_in[0];
    const float* Wemb = (const float*)d_in[1];
    const float* bemb = (const float*)d_in[2];
    const float* Wf   = (const float*)d_in[3];
    const float* bfv  = (const float*)d_in[4];
    const float* Wi   = (const float*)d_in[5];
    const float* biv  = (const float*)d_in[6];
    const float* Wc   = (const float*)d_in[7];
    const float* bcv  = (const float*)d_in[8];
    const float* Wo   = (const float*)d_in[9];
    const float* bov  = (const float*)d_in[10];
    const float* Wout = (const float*)d_in[11];
    const float* bout = (const float*)d_in[12];
    float* out = (float*)d_out;

    hipLaunchKernelGGL(lstm_fused, dim3(B_ / 16), dim3(256), 0, stream,
                       x, Wemb, bemb, Wf, bfv, Wi, biv, Wc, bcv, Wo, bov,
                       Wout, bout, out);
}